// Round 8
// baseline (311.064 us; speedup 1.0000x reference)
//
#include <hip/hip_runtime.h>
#include <hip/hip_bf16.h>

// RGCN gather-mm, etype-sorted edges.
// out[v][n] = sum_{e: dst[e]=v} sum_k feat[src[e]][k] * W[etype[e]][k][n]
//
// R19: proj back to one-(tile,relation)-per-block (R11's 12512-block
// parallelism: short blocks, ONE syncthreads, no loop barriers -> R11
// sustained 4.3 TB/s vs 2.3-3.3 for every barrier-chained feat-once
// variant R12-R18), with R11's 8x feat re-fetch fixed by GRID SWIZZLE:
// bid = tile*R + r makes the 16 same-tile blocks dispatch-adjacent, so
// the 33KB feat tile is HBM-fetched once and L3-served to the other 15
// (tight reuse distance ~2MB in-flight working set; R13's failure was
// full-sweep phase reuse, which L3 provably didn't hold). Keeps R18's
// usedb-guarded sparse stores (126MB, Poisson-verified) and in-register
// fp32->bf16 feat loads.
// Downstream (two-level dst sort + wave-per-dst gather-reduce) unchanged.
// Fallback: R4 atomic kernel (433us, known-good).

#define NTHREADS 256
#define TM 64

typedef __attribute__((ext_vector_type(8))) __bf16 bf16x8;
typedef __attribute__((ext_vector_type(4))) float f32x4;

// ---- cvt: W [R][128][64] fp32 -> Wt [R][64][128] bf16 (transposed) ----
__global__ void cvt_w_kernel(const float* __restrict__ w,
                             __bf16* __restrict__ o, int total) {
    int idx = blockIdx.x * 256 + threadIdx.x;
    if (idx >= total) return;
    int r = idx >> 13;
    int rem = idx & 8191;
    int k = rem >> 6;
    int n = rem & 63;
    o[(r << 13) + (n << 7) + k] = (__bf16)w[idx];
}

// ---- dense projection: one (128-node tile, relation) per block ----
// proj[r][node][c'] = (feat @ W[r]) permuted (c' = m*4 + nt), NT form.
// Grid linearized bid = tile*R + r: same-tile blocks adjacent -> feat
// tile L3-shared. W[r] staged once to LDS; single __syncthreads; guarded
// row stores (usedb). 4 waves x 32 nodes.
__global__ __launch_bounds__(NTHREADS)
void proj_rel_kernel(const float* __restrict__ feat, const __bf16* __restrict__ wtb,
                     const unsigned char* __restrict__ usedb,
                     int N, int R, __bf16* __restrict__ projb) {
    __shared__ __bf16 Wt[64 * 136];
    __shared__ unsigned used_l[32];

    int bid = blockIdx.x;
    int r = bid % R;
    long xt = bid / R;

    int t = threadIdx.x;
    int wave = t >> 6, lane = t & 63;
    int q = lane >> 4, m = lane & 15;
    long blk0 = xt * 128;
    long node0 = blk0 + wave * 32;

    // stage W[r] (16KB) cooperatively into LDS
    {
        const __bf16* wg = wtb + ((size_t)r << 13);
        #pragma unroll
        for (int i = 0; i < 4; i++) {
            int c = t + i * 256;
            int n = c >> 4, kc = c & 15;
            *(bf16x8*)(&Wt[n * 136 + kc * 8]) = *(const bf16x8*)(wg + n * 128 + kc * 8);
        }
    }
    // used bytes for this (r, tile): 128 bytes as 32 u32
    if (t < 32) used_l[t] = *(const unsigned*)(usedb + (size_t)r * N + blk0 + t * 4);

    // A fragments: fp32 feat -> bf16 in-register (loads overlap W staging)
    bf16x8 a[2][4];
    #pragma unroll
    for (int mt = 0; mt < 2; mt++) {
        long nd = node0 + mt * 16 + m;
        if (nd > N - 1) nd = N - 1;
        const float* arow = feat + nd * 128;
        #pragma unroll
        for (int ks = 0; ks < 4; ks++) {
            float4 fa = *(const float4*)(arow + ks * 32 + q * 8);
            float4 fb = *(const float4*)(arow + ks * 32 + q * 8 + 4);
            bf16x8 v;
            v[0] = (__bf16)fa.x; v[1] = (__bf16)fa.y; v[2] = (__bf16)fa.z; v[3] = (__bf16)fa.w;
            v[4] = (__bf16)fb.x; v[5] = (__bf16)fb.y; v[6] = (__bf16)fb.z; v[7] = (__bf16)fb.w;
            a[mt][ks] = v;
        }
    }

    __syncthreads();

    f32x4 acc[2][4] = {};
    #pragma unroll
    for (int ks = 0; ks < 4; ks++) {
        bf16x8 b0 = *(const bf16x8*)(&Wt[(0 * 16 + m) * 136 + ks * 32 + q * 8]);
        bf16x8 b1 = *(const bf16x8*)(&Wt[(1 * 16 + m) * 136 + ks * 32 + q * 8]);
        bf16x8 b2 = *(const bf16x8*)(&Wt[(2 * 16 + m) * 136 + ks * 32 + q * 8]);
        bf16x8 b3 = *(const bf16x8*)(&Wt[(3 * 16 + m) * 136 + ks * 32 + q * 8]);
        #pragma unroll
        for (int mt = 0; mt < 2; mt++) {
            acc[mt][0] = __builtin_amdgcn_mfma_f32_16x16x32_bf16(a[mt][ks], b0, acc[mt][0], 0, 0, 0);
            acc[mt][1] = __builtin_amdgcn_mfma_f32_16x16x32_bf16(a[mt][ks], b1, acc[mt][1], 0, 0, 0);
            acc[mt][2] = __builtin_amdgcn_mfma_f32_16x16x32_bf16(a[mt][ks], b2, acc[mt][2], 0, 0, 0);
            acc[mt][3] = __builtin_amdgcn_mfma_f32_16x16x32_bf16(a[mt][ks], b3, acc[mt][3], 0, 0, 0);
        }
    }

    // C/D: col = nt*16+m, node = mt*16+q*4+reg. Permuted c' = m*4+nt.
    // Store only rows some edge will read (usedb guard).
    #pragma unroll
    for (int mt = 0; mt < 2; mt++) {
        unsigned g = used_l[wave * 8 + mt * 4 + q];
        #pragma unroll
        for (int reg = 0; reg < 4; reg++) {
            long nd = node0 + mt * 16 + q * 4 + reg;
            if (nd < N && ((g >> (reg * 8)) & 1)) {
                union { unsigned long long u; __bf16 h[4]; } pk;
                pk.h[0] = (__bf16)acc[mt][0][reg];
                pk.h[1] = (__bf16)acc[mt][1][reg];
                pk.h[2] = (__bf16)acc[mt][2][reg];
                pk.h[3] = (__bf16)acc[mt][3][reg];
                *(unsigned long long*)(projb + ((size_t)r * N + nd) * 64 + m * 4) = pk.u;
            }
        }
    }
}

// ---- bucket histogram (bucket = dst>>7) ----
__global__ __launch_bounds__(1024)
void bucket_hist(const int* __restrict__ dst, int E, int* __restrict__ bhist) {
    __shared__ int lh[1024];
    int t = threadIdx.x;
    lh[t] = 0;
    __syncthreads();
    long base = (long)blockIdx.x * 8192;
    #pragma unroll
    for (int i = 0; i < 8; i++) {
        long e = base + t + 1024 * i;
        if (e < E) atomicAdd(&lh[dst[e] >> 7], 1);
    }
    __syncthreads();
    if (lh[t]) atomicAdd(&bhist[t], lh[t]);
}

// ---- scan buckets (NB <= 1024) -> boff (exclusive) + bcur; dofs[N]=E ----
__global__ __launch_bounds__(1024)
void bucket_scan(const int* __restrict__ bhist, int NB, int N, int E,
                 int* __restrict__ boff, int* __restrict__ bcur,
                 int* __restrict__ dofs) {
    __shared__ int sm[1024];
    int t = threadIdx.x;
    int v = (t < NB) ? bhist[t] : 0;
    sm[t] = v;
    __syncthreads();
    for (int s = 1; s < 1024; s <<= 1) {
        int add = (t >= s) ? sm[t - s] : 0;
        __syncthreads();
        sm[t] += add;
        __syncthreads();
    }
    if (t < NB) { int ex = sm[t] - v; boff[t] = ex; bcur[t] = ex; }
    if (t == 0) { boff[NB] = E; dofs[N] = E; }
}

// ---- LDS-binned scatter: items grouped by bucket, coalesced bursts ----
// item = (dst&127)<<24 | (etype*N + src)   [R*N < 2^24 guarded]
// Also marks usedb[etype*N+src] (idempotent byte store) for proj's guard.
__global__ __launch_bounds__(1024)
void bucket_scatter(const int* __restrict__ dst, const int* __restrict__ src,
                    const int* __restrict__ etypes, int E, int N, int NB,
                    int* __restrict__ bcur, int* __restrict__ items,
                    unsigned char* __restrict__ usedb) {
    __shared__ int lh[1024], lb[1024];
    int t = threadIdx.x;
    lh[t] = 0;
    __syncthreads();
    long base = (long)blockIdx.x * 8192;
    int bs[8], it[8];
    #pragma unroll
    for (int i = 0; i < 8; i++) {
        long e = base + t + 1024 * i;
        if (e < E) {
            int d = dst[e];
            int bkt = d >> 7;
            bs[i] = bkt;
            int pair = etypes[e] * N + src[e];
            it[i] = ((d & 127) << 24) | pair;
            usedb[pair] = 1;
            atomicAdd(&lh[bkt], 1);
        } else bs[i] = -1;
    }
    __syncthreads();
    for (int bb = t; bb < NB; bb += 1024) {
        int c = lh[bb];
        lb[bb] = c ? atomicAdd(&bcur[bb], c) : 0;
        lh[bb] = 0;
    }
    __syncthreads();
    #pragma unroll
    for (int i = 0; i < 8; i++) {
        if (bs[i] >= 0) {
            int pos = lb[bs[i]] + atomicAdd(&lh[bs[i]], 1);
            items[pos] = it[i];
        }
    }
}

// ---- refine: exact-dst order within each bucket (LDS counting sort) ----
// Emits pidx (dst-sorted proj-row indices) + per-dst offsets dofs[v].
// All global writes confined to this bucket's windows (L2-absorbed).
__global__ __launch_bounds__(256)
void refine_kernel(const int* __restrict__ boff, const int* __restrict__ items,
                   int N, int* __restrict__ pidx, int* __restrict__ dofs) {
    __shared__ int h[128], sc[128], cur[128];
    int b = blockIdx.x, t = threadIdx.x;
    int j0 = boff[b], j1 = boff[b + 1];
    if (t < 128) h[t] = 0;
    __syncthreads();
    for (int j = j0 + t; j < j1; j += 256)
        atomicAdd(&h[((unsigned)items[j]) >> 24], 1);
    __syncthreads();
    if (t < 128) sc[t] = h[t];
    __syncthreads();
    for (int s = 1; s < 128; s <<= 1) {            // inclusive scan
        int add = (t >= s && t < 128) ? sc[t - s] : 0;
        __syncthreads();
        if (t < 128) sc[t] += add;
        __syncthreads();
    }
    if (t < 128) {
        int ex = sc[t] - h[t];                     // exclusive
        cur[t] = ex;
        int v = (b << 7) + t;
        if (v < N) dofs[v] = j0 + ex;
    }
    __syncthreads();
    for (int j = j0 + t; j < j1; j += 256) {
        int it = items[j];
        int dl = ((unsigned)it) >> 24;
        int pos = j0 + atomicAdd(&cur[dl], 1);
        pidx[pos] = it & 0xFFFFFF;
    }
}

// ---- wave-per-dst gather-reduce (R9, proven) over permuted proj rows ----
__global__ __launch_bounds__(256)
void reduce_kernel(const int* __restrict__ dofs, const int* __restrict__ pidx,
                   const __bf16* __restrict__ projb, int N, float* __restrict__ out) {
    int gid = blockIdx.x * 256 + threadIdx.x;
    int w = gid >> 6, lane = gid & 63;
    int nw = (gridDim.x * 256) >> 6;
    int sub = lane >> 3, c8 = lane & 7;
    for (int v = w; v < N; v += nw) {
        int j0 = dofs[v], j1 = dofs[v + 1];
        float acc[8] = {0.f, 0.f, 0.f, 0.f, 0.f, 0.f, 0.f, 0.f};
        for (int j = j0 + sub; j < j1; j += 8) {
            int p = pidx[j];
            bf16x8 val = *(const bf16x8*)(projb + (size_t)p * 64 + c8 * 8);
            #pragma unroll
            for (int i = 0; i < 8; i++) acc[i] += (float)val[i];
        }
        #pragma unroll
        for (int mask = 8; mask <= 32; mask <<= 1) {
            #pragma unroll
            for (int i = 0; i < 8; i++) acc[i] += __shfl_xor(acc[i], mask, 64);
        }
        if (sub == 0) {
            float* orow = out + (size_t)v * 64;
            #pragma unroll
            for (int i = 0; i < 8; i++) {
                int cp = c8 * 8 + i;
                orow[(cp & 3) * 16 + (cp >> 2)] = acc[i];
            }
        }
    }
}

// ---- fallback: atomic scatter (R4, known-good 433us; no ws use) ----
__global__ __launch_bounds__(NTHREADS)
void rgcn_atomic(const float* __restrict__ feat, const float* __restrict__ weight,
                 const int* __restrict__ src, const int* __restrict__ dst,
                 const int* __restrict__ etypes, int E,
                 float* __restrict__ out) {
    __shared__ __bf16 Wt[64 * 136];
    int b = blockIdx.x;
    int e0 = b * TM;
    int t = threadIdx.x;
    int wave = t >> 6, lane = t & 63;
    int q = lane >> 4, m = lane & 15;
    int wbase = e0 + wave * 16;
    int last = e0 + TM - 1; if (last > E - 1) last = E - 1;
    int rmin = etypes[e0];
    int rmax = etypes[last];
    int em = wbase + m;
    bool rowok = em < E;
    int ei = rowok ? em : E - 1;
    int my_et = rowok ? etypes[em] : -1;
    const float* arow = feat + (long)src[ei] * 128;
    bf16x8 a[4];
    #pragma unroll
    for (int ks = 0; ks < 4; ks++) {
        float4 fa = *(const float4*)(arow + ks * 32 + q * 8);
        float4 fb = *(const float4*)(arow + ks * 32 + q * 8 + 4);
        bf16x8 v;
        v[0] = (__bf16)fa.x; v[1] = (__bf16)fa.y;
        v[2] = (__bf16)fa.z; v[3] = (__bf16)fa.w;
        v[4] = (__bf16)fb.x; v[5] = (__bf16)fb.y;
        v[6] = (__bf16)fb.z; v[7] = (__bf16)fb.w;
        a[ks] = v;
    }
    f32x4 acc0 = {0.f, 0.f, 0.f, 0.f};
    f32x4 acc1 = {0.f, 0.f, 0.f, 0.f};
    f32x4 acc2 = {0.f, 0.f, 0.f, 0.f};
    f32x4 acc3 = {0.f, 0.f, 0.f, 0.f};
    for (int r = rmin; r <= rmax; ++r) {
        if (r != rmin) __syncthreads();
        const float* wg = weight + (r << 13);
        for (int p = t; p < 4096; p += NTHREADS) {
            int n = p & 63, kh = p >> 6;
            float w0 = wg[(kh * 2) * 64 + n];
            float w1 = wg[(kh * 2 + 1) * 64 + n];
            union { unsigned u; __bf16 h[2]; } pk;
            pk.h[0] = (__bf16)w0; pk.h[1] = (__bf16)w1;
            *(unsigned*)&Wt[n * 136 + kh * 2] = pk.u;
        }
        __syncthreads();
        bool on = (my_et == r);
        #pragma unroll
        for (int ks = 0; ks < 4; ks++) {
            bf16x8 af = a[ks];
            if (!on) {
                #pragma unroll
                for (int j = 0; j < 8; j++) af[j] = (__bf16)0.f;
            }
            bf16x8 b0 = *(const bf16x8*)(&Wt[(0 * 16 + m) * 136 + ks * 32 + q * 8]);
            bf16x8 b1 = *(const bf16x8*)(&Wt[(1 * 16 + m) * 136 + ks * 32 + q * 8]);
            bf16x8 b2 = *(const bf16x8*)(&Wt[(2 * 16 + m) * 136 + ks * 32 + q * 8]);
            bf16x8 b3 = *(const bf16x8*)(&Wt[(3 * 16 + m) * 136 + ks * 32 + q * 8]);
            acc0 = __builtin_amdgcn_mfma_f32_16x16x32_bf16(af, b0, acc0, 0, 0, 0);
            acc1 = __builtin_amdgcn_mfma_f32_16x16x32_bf16(af, b1, acc1, 0, 0, 0);
            acc2 = __builtin_amdgcn_mfma_f32_16x16x32_bf16(af, b2, acc2, 0, 0, 0);
            acc3 = __builtin_amdgcn_mfma_f32_16x16x32_bf16(af, b3, acc3, 0, 0, 0);
        }
    }
    #pragma unroll
    for (int reg = 0; reg < 4; reg++) {
        int er = wbase + q * 4 + reg;
        if (er < E) {
            float* orow = out + (long)dst[er] * 64;
            unsafeAtomicAdd(orow + 0 * 16 + m, acc0[reg]);
            unsafeAtomicAdd(orow + 1 * 16 + m, acc1[reg]);
            unsafeAtomicAdd(orow + 2 * 16 + m, acc2[reg]);
            unsafeAtomicAdd(orow + 3 * 16 + m, acc3[reg]);
        }
    }
}

extern "C" void kernel_launch(void* const* d_in, const int* in_sizes, int n_in,
                              void* d_out, int out_size, void* d_ws, size_t ws_size,
                              hipStream_t stream) {
    const float* feat   = (const float*)d_in[0];
    const float* weight = (const float*)d_in[1];
    const int*   src    = (const int*)d_in[2];
    const int*   dst    = (const int*)d_in[3];
    const int*   etypes = (const int*)d_in[4];
    float* out = (float*)d_out;

    int nfeat = in_sizes[0];
    int nw    = in_sizes[1];
    int E     = in_sizes[2];
    int N     = nfeat / 128;
    int R     = nw >> 13;
    int NB    = (N + 127) >> 7;      // buckets of 128 dsts

    // ws layout (256B-aligned slabs)
    size_t o = 0;
    auto take = [&](size_t bytes) { size_t r = o; o = (o + bytes + 255) & ~(size_t)255; return r; };
    size_t o_bhist = take((size_t)NB * 4);
    size_t o_usedb = take((size_t)R * N);          // used (r,src) byte map
    size_t o_boff  = take((size_t)(NB + 1) * 4);
    size_t o_bcur  = take((size_t)NB * 4);
    size_t o_dofs  = take((size_t)(N + 1) * 4);
    size_t o_items = take((size_t)E * 4);
    size_t o_pidx  = take((size_t)E * 4);
    size_t o_wtb   = take((size_t)nw * 2);
    size_t o_projb = take((size_t)R * N * 64 * 2);
    size_t need = o;

    bool fast = (ws_size >= need) && (NB <= 1024) && ((size_t)R * N < (1u << 24))
                && (R <= 16) && ((N & 3) == 0);

    if (fast) {
        char* ws = (char*)d_ws;
        int* bhist = (int*)(ws + o_bhist);
        unsigned char* usedb = (unsigned char*)(ws + o_usedb);
        int* boff  = (int*)(ws + o_boff);
        int* bcur  = (int*)(ws + o_bcur);
        int* dofs  = (int*)(ws + o_dofs);
        int* items = (int*)(ws + o_items);
        int* pidx  = (int*)(ws + o_pidx);
        __bf16* wtb   = (__bf16*)(ws + o_wtb);
        __bf16* projb = (__bf16*)(ws + o_projb);

        int cgrid = (int)(((long)E + 8191) / 8192);

        hipMemsetAsync(bhist, 0, (size_t)NB * 4, stream);
        hipMemsetAsync(usedb, 0, (size_t)R * N, stream);
        bucket_hist<<<cgrid, 1024, 0, stream>>>(dst, E, bhist);
        bucket_scan<<<1, 1024, 0, stream>>>(bhist, NB, N, E, boff, bcur, dofs);
        bucket_scatter<<<cgrid, 1024, 0, stream>>>(dst, src, etypes, E, N, NB, bcur, items, usedb);
        refine_kernel<<<NB, 256, 0, stream>>>(boff, items, N, pidx, dofs);
        cvt_w_kernel<<<(nw + 255) / 256, 256, 0, stream>>>(weight, wtb, nw);

        int nblk = ((N + 127) / 128) * R;
        proj_rel_kernel<<<nblk, NTHREADS, 0, stream>>>(feat, wtb, usedb, N, R, projb);
        reduce_kernel<<<2048, 256, 0, stream>>>(dofs, pidx, projb, N, out);
    } else {
        hipMemsetAsync(d_out, 0, (size_t)out_size * sizeof(float), stream);
        int mgrid = (E + TM - 1) / TM;
        rgcn_atomic<<<mgrid, NTHREADS, 0, stream>>>(feat, weight, src, dst, etypes, E, out);
    }
}

// Round 9
// 252.612 us; speedup vs baseline: 1.2314x; 1.2314x over previous
//
#include <hip/hip_runtime.h>
#include <hip/hip_bf16.h>

// RGCN gather-mm, etype-sorted edges.
// out[v][n] = sum_{e: dst[e]=v} sum_k feat[src[e]][k] * W[etype[e]][k][n]
//
// R20: proj reverted to R18 (best: 67us, FETCH=28MB compulsory, WRITE=126MB
// usedb-sparse; R19's tile*R+r grid swizzle did NOT get L3 feat sharing --
// FETCH 201MB, 126us). New target: reduce_kernel. Budget accounting shows
// non-proj time stuck at ~185-190us across R11-R18; traffic bounds put the
// sort chain at ~60us => reduce ~125us at only ~1.6 TB/s. Cause: whole wave
// serializes per dst (avg degree 16 -> 2-iter gather loop, then a 24-op
// shuffle tree + store). Fix: one dst per 8-LANE SUB-GROUP -- 8 independent
// dsts in flight per wave, 8 lanes cover the 128B row (16B/lane), edge loop
// unrolled x2 (16 outstanding gathers/wave), no shuffle tree (each lane owns
// its 8 out columns, stores directly). Grid sized ~1 dst per sub-group.
// Fallback: R4 atomic kernel (433us, known-good).

#define NTHREADS 256
#define TM 64

typedef __attribute__((ext_vector_type(8))) __bf16 bf16x8;
typedef __attribute__((ext_vector_type(4))) float f32x4;

// ---- cvt: W [R][128][64] fp32 -> Wt [R][64][128] bf16 (transposed) ----
__global__ void cvt_w_kernel(const float* __restrict__ w,
                             __bf16* __restrict__ o, int total) {
    int idx = blockIdx.x * 256 + threadIdx.x;
    if (idx >= total) return;
    int r = idx >> 13;
    int rem = idx & 8191;
    int k = rem >> 6;
    int n = rem & 63;
    o[(r << 13) + (n << 7) + k] = (__bf16)w[idx];
}

// ---- dense projection: all relations per block, LDS dbuf, raw barriers,
// ---- used-row-guarded stores (R18, proven 67us) ----
__global__ __launch_bounds__(NTHREADS)
void proj_all_kernel(const float* __restrict__ feat, const __bf16* __restrict__ wtb,
                     const unsigned char* __restrict__ usedb,
                     int N, int R, __bf16* __restrict__ projb) {
    __shared__ __bf16 Wt[2][64 * 136];
    __shared__ unsigned used_l[16 * 32];   // R<=16 x 128 bytes, as u32

    int t = threadIdx.x;
    int wave = t >> 6, lane = t & 63;
    int q = lane >> 4, m = lane & 15;
    long blk0 = (long)blockIdx.x * 128;
    long node0 = blk0 + wave * 32;

    // preload used bytes for this block's 128 nodes x R relations
    for (int c = t; c < R * 32; c += NTHREADS) {
        int rr = c >> 5, i = c & 31;
        used_l[rr * 32 + i] = *(const unsigned*)(usedb + (size_t)rr * N + blk0 + i * 4);
    }

    // A fragments: fp32 feat -> bf16, loaded once for all R relations.
    bf16x8 a[2][4];
    #pragma unroll
    for (int mt = 0; mt < 2; mt++) {
        long nd = node0 + mt * 16 + m;
        if (nd > N - 1) nd = N - 1;
        const float* arow = feat + nd * 128;
        #pragma unroll
        for (int ks = 0; ks < 4; ks++) {
            float4 fa = *(const float4*)(arow + ks * 32 + q * 8);
            float4 fb = *(const float4*)(arow + ks * 32 + q * 8 + 4);
            bf16x8 v;
            v[0] = (__bf16)fa.x; v[1] = (__bf16)fa.y; v[2] = (__bf16)fa.z; v[3] = (__bf16)fa.w;
            v[4] = (__bf16)fb.x; v[5] = (__bf16)fb.y; v[6] = (__bf16)fb.z; v[7] = (__bf16)fb.w;
            a[mt][ks] = v;
        }
    }

    // stage r=0 into buffer 0
    {
        const __bf16* wg = wtb;
        #pragma unroll
        for (int i = 0; i < 4; i++) {
            int c = t + i * 256;
            int n = c >> 4, kc = c & 15;
            *(bf16x8*)(&Wt[0][n * 136 + kc * 8]) = *(const bf16x8*)(wg + n * 128 + kc * 8);
        }
    }
    asm volatile("s_waitcnt lgkmcnt(0)" ::: "memory");
    __builtin_amdgcn_s_barrier();
    __builtin_amdgcn_sched_barrier(0);

    for (int r = 0; r < R; r++) {
        int cur = r & 1, nxt = cur ^ 1;
        bool pf = (r + 1 < R);

        // T14 async-STAGE: issue next-relation W loads now; write to LDS late.
        bf16x8 wreg[4];
        if (pf) {
            const __bf16* wg = wtb + ((size_t)(r + 1) << 13);
            #pragma unroll
            for (int i = 0; i < 4; i++) {
                int c = t + i * 256;
                int n = c >> 4, kc = c & 15;
                wreg[i] = *(const bf16x8*)(wg + n * 128 + kc * 8);
            }
        }

        f32x4 acc[2][4] = {};
        #pragma unroll
        for (int ks = 0; ks < 4; ks++) {
            bf16x8 b0 = *(const bf16x8*)(&Wt[cur][(0 * 16 + m) * 136 + ks * 32 + q * 8]);
            bf16x8 b1 = *(const bf16x8*)(&Wt[cur][(1 * 16 + m) * 136 + ks * 32 + q * 8]);
            bf16x8 b2 = *(const bf16x8*)(&Wt[cur][(2 * 16 + m) * 136 + ks * 32 + q * 8]);
            bf16x8 b3 = *(const bf16x8*)(&Wt[cur][(3 * 16 + m) * 136 + ks * 32 + q * 8]);
            #pragma unroll
            for (int mt = 0; mt < 2; mt++) {
                acc[mt][0] = __builtin_amdgcn_mfma_f32_16x16x32_bf16(a[mt][ks], b0, acc[mt][0], 0, 0, 0);
                acc[mt][1] = __builtin_amdgcn_mfma_f32_16x16x32_bf16(a[mt][ks], b1, acc[mt][1], 0, 0, 0);
                acc[mt][2] = __builtin_amdgcn_mfma_f32_16x16x32_bf16(a[mt][ks], b2, acc[mt][2], 0, 0, 0);
                acc[mt][3] = __builtin_amdgcn_mfma_f32_16x16x32_bf16(a[mt][ks], b3, acc[mt][3], 0, 0, 0);
            }
        }

        // C/D: col = nt*16+m, node = mt*16+q*4+reg. Permuted c' = m*4+nt.
        // Store only rows some edge will read (usedb guard).
        #pragma unroll
        for (int mt = 0; mt < 2; mt++) {
            unsigned g = used_l[r * 32 + ((wave * 32 + mt * 16 + q * 4) >> 2)];
            #pragma unroll
            for (int reg = 0; reg < 4; reg++) {
                long nd = node0 + mt * 16 + q * 4 + reg;
                if (nd < N && ((g >> (reg * 8)) & 1)) {
                    union { unsigned long long u; __bf16 h[4]; } pk;
                    pk.h[0] = (__bf16)acc[mt][0][reg];
                    pk.h[1] = (__bf16)acc[mt][1][reg];
                    pk.h[2] = (__bf16)acc[mt][2][reg];
                    pk.h[3] = (__bf16)acc[mt][3][reg];
                    *(unsigned long long*)(projb + ((size_t)r * N + nd) * 64 + m * 4) = pk.u;
                }
            }
        }

        if (pf) {
            #pragma unroll
            for (int i = 0; i < 4; i++) {
                int c = t + i * 256;
                int n = c >> 4, kc = c & 15;
                *(bf16x8*)(&Wt[nxt][n * 136 + kc * 8]) = wreg[i];
            }
            asm volatile("s_waitcnt lgkmcnt(0)" ::: "memory");
            __builtin_amdgcn_s_barrier();
            __builtin_amdgcn_sched_barrier(0);
        }
    }
}

// ---- bucket histogram (bucket = dst>>7) ----
__global__ __launch_bounds__(1024)
void bucket_hist(const int* __restrict__ dst, int E, int* __restrict__ bhist) {
    __shared__ int lh[1024];
    int t = threadIdx.x;
    lh[t] = 0;
    __syncthreads();
    long base = (long)blockIdx.x * 8192;
    #pragma unroll
    for (int i = 0; i < 8; i++) {
        long e = base + t + 1024 * i;
        if (e < E) atomicAdd(&lh[dst[e] >> 7], 1);
    }
    __syncthreads();
    if (lh[t]) atomicAdd(&bhist[t], lh[t]);
}

// ---- scan buckets (NB <= 1024) -> boff (exclusive) + bcur; dofs[N]=E ----
__global__ __launch_bounds__(1024)
void bucket_scan(const int* __restrict__ bhist, int NB, int N, int E,
                 int* __restrict__ boff, int* __restrict__ bcur,
                 int* __restrict__ dofs) {
    __shared__ int sm[1024];
    int t = threadIdx.x;
    int v = (t < NB) ? bhist[t] : 0;
    sm[t] = v;
    __syncthreads();
    for (int s = 1; s < 1024; s <<= 1) {
        int add = (t >= s) ? sm[t - s] : 0;
        __syncthreads();
        sm[t] += add;
        __syncthreads();
    }
    if (t < NB) { int ex = sm[t] - v; boff[t] = ex; bcur[t] = ex; }
    if (t == 0) { boff[NB] = E; dofs[N] = E; }
}

// ---- LDS-binned scatter: items grouped by bucket, coalesced bursts ----
// item = (dst&127)<<24 | (etype*N + src)   [R*N < 2^24 guarded]
// Also marks usedb[etype*N+src] (idempotent byte store) for proj's guard.
__global__ __launch_bounds__(1024)
void bucket_scatter(const int* __restrict__ dst, const int* __restrict__ src,
                    const int* __restrict__ etypes, int E, int N, int NB,
                    int* __restrict__ bcur, int* __restrict__ items,
                    unsigned char* __restrict__ usedb) {
    __shared__ int lh[1024], lb[1024];
    int t = threadIdx.x;
    lh[t] = 0;
    __syncthreads();
    long base = (long)blockIdx.x * 8192;
    int bs[8], it[8];
    #pragma unroll
    for (int i = 0; i < 8; i++) {
        long e = base + t + 1024 * i;
        if (e < E) {
            int d = dst[e];
            int bkt = d >> 7;
            bs[i] = bkt;
            int pair = etypes[e] * N + src[e];
            it[i] = ((d & 127) << 24) | pair;
            usedb[pair] = 1;
            atomicAdd(&lh[bkt], 1);
        } else bs[i] = -1;
    }
    __syncthreads();
    for (int bb = t; bb < NB; bb += 1024) {
        int c = lh[bb];
        lb[bb] = c ? atomicAdd(&bcur[bb], c) : 0;
        lh[bb] = 0;
    }
    __syncthreads();
    #pragma unroll
    for (int i = 0; i < 8; i++) {
        if (bs[i] >= 0) {
            int pos = lb[bs[i]] + atomicAdd(&lh[bs[i]], 1);
            items[pos] = it[i];
        }
    }
}

// ---- refine: exact-dst order within each bucket (LDS counting sort) ----
__global__ __launch_bounds__(256)
void refine_kernel(const int* __restrict__ boff, const int* __restrict__ items,
                   int N, int* __restrict__ pidx, int* __restrict__ dofs) {
    __shared__ int h[128], sc[128], cur[128];
    int b = blockIdx.x, t = threadIdx.x;
    int j0 = boff[b], j1 = boff[b + 1];
    if (t < 128) h[t] = 0;
    __syncthreads();
    for (int j = j0 + t; j < j1; j += 256)
        atomicAdd(&h[((unsigned)items[j]) >> 24], 1);
    __syncthreads();
    if (t < 128) sc[t] = h[t];
    __syncthreads();
    for (int s = 1; s < 128; s <<= 1) {            // inclusive scan
        int add = (t >= s && t < 128) ? sc[t - s] : 0;
        __syncthreads();
        if (t < 128) sc[t] += add;
        __syncthreads();
    }
    if (t < 128) {
        int ex = sc[t] - h[t];                     // exclusive
        cur[t] = ex;
        int v = (b << 7) + t;
        if (v < N) dofs[v] = j0 + ex;
    }
    __syncthreads();
    for (int j = j0 + t; j < j1; j += 256) {
        int it = items[j];
        int dl = ((unsigned)it) >> 24;
        int pos = j0 + atomicAdd(&cur[dl], 1);
        pidx[pos] = it & 0xFFFFFF;
    }
}

// ---- gather-reduce: one dst per 8-lane sub-group (R20) ----
// Each sub-group's 8 lanes cover the 128B proj row (16B/lane); 8 independent
// dsts per wave + x2 edge unroll => up to 16 outstanding row-gathers/wave.
// No shuffle tree: lane owns out columns c8*8..c8*8+7 (permuted layout).
__global__ __launch_bounds__(256)
void reduce_kernel(const int* __restrict__ dofs, const int* __restrict__ pidx,
                   const __bf16* __restrict__ projb, int N, float* __restrict__ out) {
    int gid = blockIdx.x * 256 + threadIdx.x;
    int sg = gid >> 3, c8 = gid & 7;
    int nsg = (gridDim.x * 256) >> 3;
    for (int v = sg; v < N; v += nsg) {
        int j0 = dofs[v], j1 = dofs[v + 1];
        float acc[8] = {0.f, 0.f, 0.f, 0.f, 0.f, 0.f, 0.f, 0.f};
        int j = j0;
        for (; j + 1 < j1; j += 2) {
            int p0 = pidx[j], p1 = pidx[j + 1];
            bf16x8 v0 = *(const bf16x8*)(projb + (size_t)p0 * 64 + c8 * 8);
            bf16x8 v1 = *(const bf16x8*)(projb + (size_t)p1 * 64 + c8 * 8);
            #pragma unroll
            for (int i = 0; i < 8; i++) acc[i] += (float)v0[i] + (float)v1[i];
        }
        if (j < j1) {
            int p = pidx[j];
            bf16x8 v0 = *(const bf16x8*)(projb + (size_t)p * 64 + c8 * 8);
            #pragma unroll
            for (int i = 0; i < 8; i++) acc[i] += (float)v0[i];
        }
        float* orow = out + (size_t)v * 64;
        #pragma unroll
        for (int i = 0; i < 8; i++) {
            int cp = c8 * 8 + i;
            orow[(cp & 3) * 16 + (cp >> 2)] = acc[i];
        }
    }
}

// ---- fallback: atomic scatter (R4, known-good 433us; no ws use) ----
__global__ __launch_bounds__(NTHREADS)
void rgcn_atomic(const float* __restrict__ feat, const float* __restrict__ weight,
                 const int* __restrict__ src, const int* __restrict__ dst,
                 const int* __restrict__ etypes, int E,
                 float* __restrict__ out) {
    __shared__ __bf16 Wt[64 * 136];
    int b = blockIdx.x;
    int e0 = b * TM;
    int t = threadIdx.x;
    int wave = t >> 6, lane = t & 63;
    int q = lane >> 4, m = lane & 15;
    int wbase = e0 + wave * 16;
    int last = e0 + TM - 1; if (last > E - 1) last = E - 1;
    int rmin = etypes[e0];
    int rmax = etypes[last];
    int em = wbase + m;
    bool rowok = em < E;
    int ei = rowok ? em : E - 1;
    int my_et = rowok ? etypes[em] : -1;
    const float* arow = feat + (long)src[ei] * 128;
    bf16x8 a[4];
    #pragma unroll
    for (int ks = 0; ks < 4; ks++) {
        float4 fa = *(const float4*)(arow + ks * 32 + q * 8);
        float4 fb = *(const float4*)(arow + ks * 32 + q * 8 + 4);
        bf16x8 v;
        v[0] = (__bf16)fa.x; v[1] = (__bf16)fa.y;
        v[2] = (__bf16)fa.z; v[3] = (__bf16)fa.w;
        v[4] = (__bf16)fb.x; v[5] = (__bf16)fb.y;
        v[6] = (__bf16)fb.z; v[7] = (__bf16)fb.w;
        a[ks] = v;
    }
    f32x4 acc0 = {0.f, 0.f, 0.f, 0.f};
    f32x4 acc1 = {0.f, 0.f, 0.f, 0.f};
    f32x4 acc2 = {0.f, 0.f, 0.f, 0.f};
    f32x4 acc3 = {0.f, 0.f, 0.f, 0.f};
    for (int r = rmin; r <= rmax; ++r) {
        if (r != rmin) __syncthreads();
        const float* wg = weight + (r << 13);
        for (int p = t; p < 4096; p += NTHREADS) {
            int n = p & 63, kh = p >> 6;
            float w0 = wg[(kh * 2) * 64 + n];
            float w1 = wg[(kh * 2 + 1) * 64 + n];
            union { unsigned u; __bf16 h[2]; } pk;
            pk.h[0] = (__bf16)w0; pk.h[1] = (__bf16)w1;
            *(unsigned*)&Wt[n * 136 + kh * 2] = pk.u;
        }
        __syncthreads();
        bool on = (my_et == r);
        #pragma unroll
        for (int ks = 0; ks < 4; ks++) {
            bf16x8 af = a[ks];
            if (!on) {
                #pragma unroll
                for (int j = 0; j < 8; j++) af[j] = (__bf16)0.f;
            }
            bf16x8 b0 = *(const bf16x8*)(&Wt[(0 * 16 + m) * 136 + ks * 32 + q * 8]);
            bf16x8 b1 = *(const bf16x8*)(&Wt[(1 * 16 + m) * 136 + ks * 32 + q * 8]);
            bf16x8 b2 = *(const bf16x8*)(&Wt[(2 * 16 + m) * 136 + ks * 32 + q * 8]);
            bf16x8 b3 = *(const bf16x8*)(&Wt[(3 * 16 + m) * 136 + ks * 32 + q * 8]);
            acc0 = __builtin_amdgcn_mfma_f32_16x16x32_bf16(af, b0, acc0, 0, 0, 0);
            acc1 = __builtin_amdgcn_mfma_f32_16x16x32_bf16(af, b1, acc1, 0, 0, 0);
            acc2 = __builtin_amdgcn_mfma_f32_16x16x32_bf16(af, b2, acc2, 0, 0, 0);
            acc3 = __builtin_amdgcn_mfma_f32_16x16x32_bf16(af, b3, acc3, 0, 0, 0);
        }
    }
    #pragma unroll
    for (int reg = 0; reg < 4; reg++) {
        int er = wbase + q * 4 + reg;
        if (er < E) {
            float* orow = out + (long)dst[er] * 64;
            unsafeAtomicAdd(orow + 0 * 16 + m, acc0[reg]);
            unsafeAtomicAdd(orow + 1 * 16 + m, acc1[reg]);
            unsafeAtomicAdd(orow + 2 * 16 + m, acc2[reg]);
            unsafeAtomicAdd(orow + 3 * 16 + m, acc3[reg]);
        }
    }
}

extern "C" void kernel_launch(void* const* d_in, const int* in_sizes, int n_in,
                              void* d_out, int out_size, void* d_ws, size_t ws_size,
                              hipStream_t stream) {
    const float* feat   = (const float*)d_in[0];
    const float* weight = (const float*)d_in[1];
    const int*   src    = (const int*)d_in[2];
    const int*   dst    = (const int*)d_in[3];
    const int*   etypes = (const int*)d_in[4];
    float* out = (float*)d_out;

    int nfeat = in_sizes[0];
    int nw    = in_sizes[1];
    int E     = in_sizes[2];
    int N     = nfeat / 128;
    int R     = nw >> 13;
    int NB    = (N + 127) >> 7;      // buckets of 128 dsts

    // ws layout (256B-aligned slabs)
    size_t o = 0;
    auto take = [&](size_t bytes) { size_t r = o; o = (o + bytes + 255) & ~(size_t)255; return r; };
    size_t o_bhist = take((size_t)NB * 4);
    size_t o_usedb = take((size_t)R * N);          // used (r,src) byte map
    size_t o_boff  = take((size_t)(NB + 1) * 4);
    size_t o_bcur  = take((size_t)NB * 4);
    size_t o_dofs  = take((size_t)(N + 1) * 4);
    size_t o_items = take((size_t)E * 4);
    size_t o_pidx  = take((size_t)E * 4);
    size_t o_wtb   = take((size_t)nw * 2);
    size_t o_projb = take((size_t)R * N * 64 * 2);
    size_t need = o;

    bool fast = (ws_size >= need) && (NB <= 1024) && ((size_t)R * N < (1u << 24)) && (R <= 16);

    if (fast) {
        char* ws = (char*)d_ws;
        int* bhist = (int*)(ws + o_bhist);
        unsigned char* usedb = (unsigned char*)(ws + o_usedb);
        int* boff  = (int*)(ws + o_boff);
        int* bcur  = (int*)(ws + o_bcur);
        int* dofs  = (int*)(ws + o_dofs);
        int* items = (int*)(ws + o_items);
        int* pidx  = (int*)(ws + o_pidx);
        __bf16* wtb   = (__bf16*)(ws + o_wtb);
        __bf16* projb = (__bf16*)(ws + o_projb);

        int cgrid = (int)(((long)E + 8191) / 8192);

        hipMemsetAsync(bhist, 0, (size_t)NB * 4, stream);
        hipMemsetAsync(usedb, 0, (size_t)R * N, stream);
        bucket_hist<<<cgrid, 1024, 0, stream>>>(dst, E, bhist);
        bucket_scan<<<1, 1024, 0, stream>>>(bhist, NB, N, E, boff, bcur, dofs);
        bucket_scatter<<<cgrid, 1024, 0, stream>>>(dst, src, etypes, E, N, NB, bcur, items, usedb);
        refine_kernel<<<NB, 256, 0, stream>>>(boff, items, N, pidx, dofs);
        cvt_w_kernel<<<(nw + 255) / 256, 256, 0, stream>>>(weight, wtb, nw);

        proj_all_kernel<<<(N + 127) / 128, NTHREADS, 0, stream>>>(feat, wtb, usedb, N, R, projb);
        int rblk = (N + 31) / 32;          // 32 sub-groups (dsts) per 256-thr block
        reduce_kernel<<<rblk, 256, 0, stream>>>(dofs, pidx, projb, N, out);
    } else {
        hipMemsetAsync(d_out, 0, (size_t)out_size * sizeof(float), stream);
        int mgrid = (E + TM - 1) / TM;
        rgcn_atomic<<<mgrid, NTHREADS, 0, stream>>>(feat, weight, src, dst, etypes, E, out);
    }
}